// Round 9
// baseline (127.837 us; speedup 1.0000x reference)
//
#include <hip/hip_runtime.h>
#include <hip/hip_bf16.h>

// ---------------------------------------------------------------------------
// LayerNormGRUCell: B=16384, I=H=512
//   G = [x@W_i2h.T | h@W_h2h.T | x@W_hatW.T | h@W_hatU.T]  (16384 x 3072)
//   then per-row: LN segments + gates + tanh + lerp -> h_t (16384 x 512 fp32)
// ws layout (bf16 elements):
//   Wcat @ 0        (3072*512)    rows: [W_i2h;W_h2h;W_hatW;W_hatU]
//   Gb   @ 1572864  (16384*3072)
// x/h are consumed as fp32 directly by the GEMM: staged fp32 via
// global_load_lds (async path preserved -- no T14 reg-staging stall), and
// converted to bf16 at fragment-read time (ds_read fp32 -> 8 cvt -> MFMA).
// ---------------------------------------------------------------------------

using f32x4 = __attribute__((ext_vector_type(4))) float;
using s16x8 = __attribute__((ext_vector_type(8))) short;

#define WB_OFF   0ull
#define GB_OFF   1572864ull

__device__ __forceinline__ void async_load16(const void* g, void* l) {
  __builtin_amdgcn_global_load_lds(
      (const __attribute__((address_space(1))) unsigned int*)g,
      (__attribute__((address_space(3))) unsigned int*)l, 16, 0, 0);
}

__device__ __forceinline__ float bfraw2f(unsigned short u) {
  union { unsigned int i; float f; } c;
  c.i = ((unsigned int)u) << 16;
  return c.f;
}

// -------------------------- fp32 -> bf16 weights only ----------------------
// vec4 boundaries: w0 131072, w1 +131072, w2 +65536, w3 +65536 = 393216 total
__global__ __launch_bounds__(256) void convert_w_kernel(
    const float* __restrict__ w0, const float* __restrict__ w1,
    const float* __restrict__ w2, const float* __restrict__ w3,
    __hip_bfloat16* __restrict__ dst)
{
  const size_t i = (size_t)blockIdx.x * 256 + threadIdx.x;  // vec4 index
  const float* src;
  __hip_bfloat16* d;
  size_t o;
  if (i < 131072ull)      { src = w0; d = dst;            o = i; }
  else if (i < 262144ull) { src = w1; d = dst + 524288;   o = i - 131072ull; }
  else if (i < 327680ull) { src = w2; d = dst + 1048576;  o = i - 262144ull; }
  else                    { src = w3; d = dst + 1310720;  o = i - 327680ull; }
  const float4 v = *(const float4*)(src + 4 * o);
  __hip_bfloat16 t4[4] = {__float2bfloat16(v.x), __float2bfloat16(v.y),
                          __float2bfloat16(v.z), __float2bfloat16(v.w)};
  *(uint2*)(d + 4 * o) = *(const uint2*)t4;
}

// -------------------------------- GEMM -------------------------------------
// 128x256 tile, BK=32, 8 waves (2Mx4N, per-wave 64x64, acc[4][4]).
// A staged as RAW FP32 via global_load_lds (ring-2, 2x16KB); converted to
// bf16 at fragment-read time (2x ds_read_b128 + 8x __float2bfloat16 per
// fragment). B staged bf16 via global_load_lds (ring-3, 3x16KB, pre-swizzled
// source). LDS = 80KB -> 2 blocks/CU (160KB exact).
// Counted vmcnt (T4): per iter issue A(t+1) then B(t+2); entry queue
// (oldest->newest) = [B(t)], A(t), B(t+1) -> entry vmcnt(2) confirms A(t)+B(t),
// leaves B(t+1) in flight; vmcnt(0) only at t=15.
// T1 XCD swizzle, T2 XOR swizzles, T5 setprio. Full K-loop unroll.
//
// A-LDS slot: [128 rows][128 B fp32]; physical 16B chunk cb of row holds
// global k-bytes cb ^ swzA(row), swzA = (row&7)<<4  (8 slots per 8 rows ->
// 2 lanes/bank on frag reads = free). Note row&7 == lr&7 on the read side.
// B-LDS slot: [256 rows][64 B bf16]; swzB = ((row>>1)&3)<<4 (round-7, 0 conf).
//
// WAR safety: A(t+1) targets slot (t+1)&1 = (t-1)&1; B(t+2) targets slot
// (t+2)%3 = (t-1)%3 -- both fully read before this iter's entry barrier.

#define A_SLOT   16384      // 128*128
#define B_BASE   32768      // after 2 A slots
#define B_SLOT   16384      // 256*64

__device__ __forceinline__ void stage_Afp(const float* base, char* slot,
                                          int koffB, int tid) {
#pragma unroll
  for (int i = 0; i < 2; ++i) {
    const int row = i * 64 + (tid >> 3);
    const int cb  = (tid & 7) * 16;
    const int src = cb ^ ((row & 7) << 4);           // pre-swizzled col byte
    async_load16((const char*)base + (size_t)row * 2048 + koffB + src,
                 slot + i * 8192 + tid * 16);
  }
}

__device__ __forceinline__ void stage_B(const char* base, char* slot,
                                        int koff, int wave, int lane) {
#pragma unroll
  for (int i = 0; i < 2; ++i) {
    const int c = wave * 2 + i;
    const int row  = c * 16 + (lane >> 2);
    const int colb = ((lane & 3) * 16) ^ (((lane >> 3) & 3) << 4);  // pre-swz
    async_load16(base + (size_t)row * 1024 + koff + colb,
                 slot + c * 1024 + lane * 16);
  }
}

__global__ __launch_bounds__(512, 4) void gemm_kernel(
    const float* __restrict__ xf,
    const float* __restrict__ hf,
    const __hip_bfloat16* __restrict__ Wb,
    __hip_bfloat16* __restrict__ G)
{
  // T1: bijective XCD swizzle; nwg=1536, 1536%8==0, chunk=192 wgs/XCD.
  const int bid = blockIdx.x;
  const int wg  = (bid & 7) * 192 + (bid >> 3);
  const int ntl = wg % 12, mtl = wg / 12;
  const int m0 = mtl * 128, n0 = ntl * 256;
  const int seg = n0 >> 9;  // 512-wide segments: 0,1,4 -> x ; 2,3,5 -> h
  const float* A = (seg < 2 || seg == 4) ? xf : hf;

  __shared__ __align__(16) char lds[81920];  // A ring-2 (32K) + B ring-3 (48K)

  const int tid  = threadIdx.x;
  const int lane = tid & 63;
  const int wave = tid >> 6;
  const int wm = wave >> 2, wn = wave & 3;   // 2 x 4 wave grid, 64x64 each

  const float* Afp = A + (size_t)m0 * 512;          // fp32, row stride 512
  const char*  Bb  = (const char*)Wb + (size_t)n0 * 1024;

  const int lk  = (lane >> 4) * 16;                // bf16 k-quarter byte off
  const int lr  = lane & 15;
  const int rdk = lk ^ (((lr >> 1) & 3) << 4);     // B read swizzle
  const int akb = (lane >> 4) * 32;                // fp32 k-quarter byte off
  const int asw = (lr & 7) << 4;                   // A read swizzle (per-lane)

  auto rdA = [&](int fm, int slot) {
    const char* rb = lds + slot * A_SLOT + (wm * 64 + fm * 16 + lr) * 128;
    const f32x4 u = *(const f32x4*)(rb + (akb ^ asw));
    const f32x4 v = *(const f32x4*)(rb + ((akb + 16) ^ asw));
    union { s16x8 s; __hip_bfloat16 b[8]; } o;
    o.b[0] = __float2bfloat16(u[0]); o.b[1] = __float2bfloat16(u[1]);
    o.b[2] = __float2bfloat16(u[2]); o.b[3] = __float2bfloat16(u[3]);
    o.b[4] = __float2bfloat16(v[0]); o.b[5] = __float2bfloat16(v[1]);
    o.b[6] = __float2bfloat16(v[2]); o.b[7] = __float2bfloat16(v[3]);
    return o.s;
  };
  auto rdB = [&](int fn, int slot) {
    return *(const s16x8*)(lds + B_BASE + slot * B_SLOT +
                           (wn * 64 + fn * 16 + lr) * 64 + rdk);
  };

  f32x4 acc[4][4];
#pragma unroll
  for (int i = 0; i < 4; ++i)
#pragma unroll
    for (int j = 0; j < 4; ++j) acc[i][j] = (f32x4){0.f, 0.f, 0.f, 0.f};

  // prologue: A(0), B(0), B(1). Queue: A0 A0 B0 B0 B1 B1 -> vmcnt(2).
  stage_Afp(Afp, lds, 0, tid);
  stage_B(Bb, lds + B_BASE, 0, wave, lane);
  stage_B(Bb, lds + B_BASE + B_SLOT, 64, wave, lane);
  asm volatile("s_waitcnt vmcnt(2)" ::: "memory");
  __builtin_amdgcn_s_barrier();

  // K = 512 = 16 ktiles of 32, fully unrolled (static slot indices)
#pragma unroll
  for (int t = 0; t < 16; ++t) {
    if (t > 0) {
      // entry queue (oldest->newest): B(t), A(t), B(t+1)
      if (t <= 14) asm volatile("s_waitcnt vmcnt(2)" ::: "memory");
      else         asm volatile("s_waitcnt vmcnt(0)" ::: "memory");
      __builtin_amdgcn_s_barrier();
    }

    // issue next staging first (A then B keeps the vmcnt queue ordering)
    if (t <= 14) stage_Afp(Afp, lds + ((t + 1) & 1) * A_SLOT,
                           (t + 1) * 128, tid);
    if (t <= 13) stage_B(Bb, lds + B_BASE + ((t + 2) % 3) * B_SLOT,
                         (t + 2) * 64, wave, lane);

    const int bslot = t % 3, aslot = t & 1;
    s16x8 b[4], a[4];
#pragma unroll
    for (int fn = 0; fn < 4; ++fn) b[fn] = rdB(fn, bslot);
#pragma unroll
    for (int fm = 0; fm < 4; ++fm) a[fm] = rdA(fm, aslot);

    __builtin_amdgcn_s_setprio(1);
#pragma unroll
    for (int fm = 0; fm < 4; ++fm)
#pragma unroll
      for (int fn = 0; fn < 4; ++fn)
        acc[fm][fn] = __builtin_amdgcn_mfma_f32_16x16x32_bf16(
            a[fm], b[fn], acc[fm][fn], 0, 0, 0);
    __builtin_amdgcn_s_setprio(0);
  }

  // epilogue: D lane map (verified): col = lane&15, row = (lane>>4)*4 + reg
  const int mbase = m0 + wm * 64 + ((lane >> 4) << 2);
  const int nbase = n0 + wn * 64 + (lane & 15);
#pragma unroll
  for (int fm = 0; fm < 4; ++fm)
#pragma unroll
    for (int fn = 0; fn < 4; ++fn)
#pragma unroll
      for (int r = 0; r < 4; ++r)
        G[(size_t)(mbase + fm * 16 + r) * 3072 + nbase + fn * 16] =
            __float2bfloat16(acc[fm][fn][r]);
}

// ------------------------------ LN + gates ---------------------------------
__device__ __forceinline__ float4 block_red4(float4 v, float* red, int tid) {
#pragma unroll
  for (int off = 32; off; off >>= 1) {
    v.x += __shfl_down(v.x, off);
    v.y += __shfl_down(v.y, off);
    v.z += __shfl_down(v.z, off);
    v.w += __shfl_down(v.w, off);
  }
  __syncthreads();  // protect `red` against previous use
  if ((tid & 63) == 0) {
    const int w = tid >> 6;
    red[w * 4 + 0] = v.x; red[w * 4 + 1] = v.y;
    red[w * 4 + 2] = v.z; red[w * 4 + 3] = v.w;
  }
  __syncthreads();
  return make_float4(red[0] + red[4] + red[8]  + red[12],
                     red[1] + red[5] + red[9]  + red[13],
                     red[2] + red[6] + red[10] + red[14],
                     red[3] + red[7] + red[11] + red[15]);
}

__global__ __launch_bounds__(256) void ln_gate_kernel(
    const __hip_bfloat16* __restrict__ G, const float* __restrict__ h,
    const float* __restrict__ b0, const float* __restrict__ b1,
    const float* __restrict__ b2, const float* __restrict__ b3,
    float* __restrict__ out)
{
  const int row = blockIdx.x;
  const int t   = threadIdx.x;
  const unsigned short* g = (const unsigned short*)(G + (size_t)row * 3072);

  __shared__ float zr[1024];
  __shared__ float red[16];

  float v0[4], v1[4];
  {
    const ushort4 u = *(const ushort4*)(g + 4 * t);
    const float4 b = *(const float4*)(b0 + 4 * t);
    v0[0] = bfraw2f(u.x) + b.x; v0[1] = bfraw2f(u.y) + b.y;
    v0[2] = bfraw2f(u.z) + b.z; v0[3] = bfraw2f(u.w) + b.w;
  }
  {
    const ushort4 u = *(const ushort4*)(g + 1024 + 4 * t);
    const float4 b = *(const float4*)(b1 + 4 * t);
    v1[0] = bfraw2f(u.x) + b.x; v1[1] = bfraw2f(u.y) + b.y;
    v1[2] = bfraw2f(u.z) + b.z; v1[3] = bfraw2f(u.w) + b.w;
  }
  float4 a;
  a.x = v0[0] + v0[1] + v0[2] + v0[3];
  a.y = v0[0]*v0[0] + v0[1]*v0[1] + v0[2]*v0[2] + v0[3]*v0[3];
  a.z = v1[0] + v1[1] + v1[2] + v1[3];
  a.w = v1[0]*v1[0] + v1[1]*v1[1] + v1[2]*v1[2] + v1[3]*v1[3];
  const float4 r01 = block_red4(a, red, t);
  const float mu0 = r01.x * (1.f / 1024.f);
  const float mu1 = r01.z * (1.f / 1024.f);
  const float rs0 = rsqrtf(r01.y * (1.f / 1024.f) - mu0 * mu0 + 1e-5f);
  const float rs1 = rsqrtf(r01.w * (1.f / 1024.f) - mu1 * mu1 + 1e-5f);

#pragma unroll
  for (int k = 0; k < 4; ++k) {
    const float pre = (v0[k] - mu0) * rs0 + (v1[k] - mu1) * rs1;
    zr[4 * t + k] = 1.f / (1.f + __expf(-pre));
  }

  float v2[2], v3[2];
  {
    const ushort2 u = *(const ushort2*)(g + 2048 + 2 * t);
    const float2 b = *(const float2*)(b2 + 2 * t);
    v2[0] = bfraw2f(u.x) + b.x; v2[1] = bfraw2f(u.y) + b.y;
  }
  {
    const ushort2 u = *(const ushort2*)(g + 2560 + 2 * t);
    const float2 b = *(const float2*)(b3 + 2 * t);
    v3[0] = bfraw2f(u.x) + b.x; v3[1] = bfraw2f(u.y) + b.y;
  }
  a.x = v2[0] + v2[1];
  a.y = v2[0]*v2[0] + v2[1]*v2[1];
  a.z = v3[0] + v3[1];
  a.w = v3[0]*v3[0] + v3[1]*v3[1];
  const float4 r23 = block_red4(a, red, t);  // syncs also publish zr[]
  const float mu2 = r23.x * (1.f / 512.f);
  const float mu3 = r23.z * (1.f / 512.f);
  const float rs2 = rsqrtf(r23.y * (1.f / 512.f) - mu2 * mu2 + 1e-5f);
  const float rs3 = rsqrtf(r23.w * (1.f / 512.f) - mu3 * mu3 + 1e-5f);

  const float2 hv = *(const float2*)(h + (size_t)row * 512 + 2 * t);
  float o[2];
#pragma unroll
  for (int k = 0; k < 2; ++k) {
    const int j = 2 * t + k;
    const float ha = (v2[k] - mu2) * rs2;
    const float hb = (v3[k] - mu3) * rs3;
    const float hhat = tanhf(ha + zr[512 + j] * hb);
    const float z = zr[j];
    const float hvk = (k == 0) ? hv.x : hv.y;
    o[k] = (1.f - z) * hvk + z * hhat;
  }
  *(float2*)(out + (size_t)row * 512 + 2 * t) = make_float2(o[0], o[1]);
}

// ------------------------------- launcher ----------------------------------
extern "C" void kernel_launch(void* const* d_in, const int* in_sizes, int n_in,
                              void* d_out, int out_size, void* d_ws, size_t ws_size,
                              hipStream_t stream) {
  (void)in_sizes; (void)n_in; (void)out_size; (void)ws_size;
  const float* x      = (const float*)d_in[0];
  const float* h      = (const float*)d_in[1];
  const float* W_i2h  = (const float*)d_in[2];
  const float* b_i2h  = (const float*)d_in[3];
  const float* W_h2h  = (const float*)d_in[4];
  const float* b_h2h  = (const float*)d_in[5];
  const float* W_hatW = (const float*)d_in[6];
  const float* b_hatW = (const float*)d_in[7];
  const float* W_hatU = (const float*)d_in[8];
  const float* b_hatU = (const float*)d_in[9];
  float* out = (float*)d_out;
  __hip_bfloat16* ws = (__hip_bfloat16*)d_ws;

  convert_w_kernel<<<1536, 256, 0, stream>>>(W_i2h, W_h2h, W_hatW, W_hatU,
                                             ws + WB_OFF);
  gemm_kernel<<<1536, 512, 0, stream>>>(x, h, ws + WB_OFF, ws + GB_OFF);
  ln_gate_kernel<<<16384, 256, 0, stream>>>(ws + GB_OFF, h, b_i2h, b_h2h,
                                            b_hatW, b_hatU, out);
}

// Round 10
// 124.258 us; speedup vs baseline: 1.0288x; 1.0288x over previous
//
#include <hip/hip_runtime.h>
#include <hip/hip_bf16.h>

// ---------------------------------------------------------------------------
// LayerNormGRUCell: B=16384, I=H=512
//   G = [x@W_i2h.T | h@W_h2h.T | x@W_hatW.T | h@W_hatU.T]  (16384 x 3072)
//   then per-row: LN segments + gates + tanh + lerp -> h_t (16384 x 512 fp32)
// ws layout (bf16 elements):
//   Wcat @ 0        (3072*512)    rows: [W_i2h;W_h2h;W_hatW;W_hatU]
//   Gb   @ 1572864  (16384*3072)
// x/h consumed as fp32 directly by the GEMM: reg-staged with the load issued
// ONE ITERATION EARLY -- the entry vmcnt(2) already retires A(t+1) (issue
// order A before B), so the cvt+ds_write at iter t needs no extra wait and
// gets a full ktile (~3000 cyc) of latency cover (round-8 fix).
// ---------------------------------------------------------------------------

using f32x4 = __attribute__((ext_vector_type(4))) float;
using s16x8 = __attribute__((ext_vector_type(8))) short;

#define WB_OFF   0ull
#define GB_OFF   1572864ull

__device__ __forceinline__ void async_load16(const void* g, void* l) {
  __builtin_amdgcn_global_load_lds(
      (const __attribute__((address_space(1))) unsigned int*)g,
      (__attribute__((address_space(3))) unsigned int*)l, 16, 0, 0);
}

__device__ __forceinline__ float bfraw2f(unsigned short u) {
  union { unsigned int i; float f; } c;
  c.i = ((unsigned int)u) << 16;
  return c.f;
}

// -------------------------- fp32 -> bf16 weights only ----------------------
// vec4 boundaries: w0 131072, w1 +131072, w2 +65536, w3 +65536 = 393216 total
__global__ __launch_bounds__(256) void convert_w_kernel(
    const float* __restrict__ w0, const float* __restrict__ w1,
    const float* __restrict__ w2, const float* __restrict__ w3,
    __hip_bfloat16* __restrict__ dst)
{
  const size_t i = (size_t)blockIdx.x * 256 + threadIdx.x;  // vec4 index
  const float* src;
  __hip_bfloat16* d;
  size_t o;
  if (i < 131072ull)      { src = w0; d = dst;            o = i; }
  else if (i < 262144ull) { src = w1; d = dst + 524288;   o = i - 131072ull; }
  else if (i < 327680ull) { src = w2; d = dst + 1048576;  o = i - 262144ull; }
  else                    { src = w3; d = dst + 1310720;  o = i - 327680ull; }
  const float4 v = *(const float4*)(src + 4 * o);
  __hip_bfloat16 t4[4] = {__float2bfloat16(v.x), __float2bfloat16(v.y),
                          __float2bfloat16(v.z), __float2bfloat16(v.w)};
  *(uint2*)(d + 4 * o) = *(const uint2*)t4;
}

// -------------------------------- GEMM -------------------------------------
// 128x256 tile, BK=32, 8 waves (2Mx4N, per-wave 64x64, acc[4][4]).
// A: fp32 loaded to regs at iter t-1 (2x dwordx4/thread), cvt to bf16 and
//    ds_write_b128 (swizzled) at iter t -- write needs NO vmem wait because
//    the entry vmcnt(2) already retired it (A issued before B each iter).
//    A ring-3 bf16 (3x8KB).
// B: bf16 via global_load_lds, pre-swizzled source, ring-3 (3x16KB).
// LDS = 72KB -> 2 blocks/CU. Counted vmcnt(2) entries, vmcnt(0) only at t=15.
// T1 XCD swizzle, T2 XOR swizzle (round-8-proven write/read pair, 0 conf),
// T5 setprio. Full K-loop unroll.
//
// VMEM queue invariant (oldest->newest) at entry of iter t: B(t), A(t+1),
// B(t+1) -> vmcnt(2) retires B(t) [reads ok] and A(t+1) [write ok], leaves
// B(t+1) in flight. lgkmcnt(0) before barrier makes iter t-1's A ds_write
// visible to all waves.
// WAR: A write slot (t+1)%3 at iter t vs its readers at iter t-2: 2 barriers
// ago ok. B gld_lds slot (t+2)%3 at iter t vs readers at iter t-1: reads
// retired before their MFMA (lgkm) which precedes the entry barrier. ok.

#define A_SLOT   8192       // 128*64 bf16
#define B_BASE   24576      // after 3 A slots
#define B_SLOT   16384      // 256*64 bf16

__device__ __forceinline__ void stage_B(const char* base, char* slot,
                                        int koff, int wave, int lane) {
#pragma unroll
  for (int i = 0; i < 2; ++i) {
    const int c = wave * 2 + i;
    const int row  = c * 16 + (lane >> 2);
    const int colb = ((lane & 3) * 16) ^ (((lane >> 3) & 3) << 4);  // pre-swz
    async_load16(base + (size_t)row * 1024 + koff + colb,
                 slot + c * 1024 + lane * 16);
  }
}

__global__ __launch_bounds__(512, 4) void gemm_kernel(
    const float* __restrict__ xf,
    const float* __restrict__ hf,
    const __hip_bfloat16* __restrict__ Wb,
    __hip_bfloat16* __restrict__ G)
{
  // T1: bijective XCD swizzle; nwg=1536, 1536%8==0, chunk=192 wgs/XCD.
  const int bid = blockIdx.x;
  const int wg  = (bid & 7) * 192 + (bid >> 3);
  const int ntl = wg % 12, mtl = wg / 12;
  const int m0 = mtl * 128, n0 = ntl * 256;
  const int seg = n0 >> 9;  // 512-wide segments: 0,1,4 -> x ; 2,3,5 -> h
  const float* A = (seg < 2 || seg == 4) ? xf : hf;

  __shared__ __align__(16) char lds[73728];  // A ring-3 (24K) + B ring-3 (48K)

  const int tid  = threadIdx.x;
  const int lane = tid & 63;
  const int wave = tid >> 6;
  const int wm = wave >> 2, wn = wave & 3;   // 2 x 4 wave grid, 64x64 each

  const float* Afp = A + (size_t)m0 * 512;          // fp32, row stride 512
  const char*  Bb  = (const char*)Wb + (size_t)n0 * 1024;

  // A staging addressing (round-8-proven): thread -> row tid>>2, 8 fp32 at
  // col (tid&3)*8; LDS write at XOR-swizzled 16B slot.
  const int arow = tid >> 2;
  const float* aptr = Afp + (size_t)arow * 512 + (tid & 3) * 8;
  const int awr_off = arow * 64 + (((tid & 3) * 16) ^ (((arow >> 1) & 3) << 4));

  const int lk  = (lane >> 4) * 16;                // bf16 k-quarter byte off
  const int lr  = lane & 15;
  const int rdk = lk ^ (((lr >> 1) & 3) << 4);     // read swizzle (A and B)

  auto rdA = [&](int fm, int slot) {
    return *(const s16x8*)(lds + slot * A_SLOT +
                           (wm * 64 + fm * 16 + lr) * 64 + rdk);
  };
  auto rdB = [&](int fn, int slot) {
    return *(const s16x8*)(lds + B_BASE + slot * B_SLOT +
                           (wn * 64 + fn * 16 + lr) * 64 + rdk);
  };
  auto loadA = [&](int s, float4& f0, float4& f1) {  // fp32 for ktile s
    const float* p = aptr + s * 32;
    f0 = *(const float4*)p;
    f1 = *(const float4*)(p + 4);
  };
  auto writeA = [&](int s, const float4& f0, const float4& f1) {
    union { s16x8 v; __hip_bfloat16 b[8]; } u;
    u.b[0] = __float2bfloat16(f0.x); u.b[1] = __float2bfloat16(f0.y);
    u.b[2] = __float2bfloat16(f0.z); u.b[3] = __float2bfloat16(f0.w);
    u.b[4] = __float2bfloat16(f1.x); u.b[5] = __float2bfloat16(f1.y);
    u.b[6] = __float2bfloat16(f1.z); u.b[7] = __float2bfloat16(f1.w);
    *(s16x8*)(lds + (s % 3) * A_SLOT + awr_off) = u.v;
  };

  f32x4 acc[4][4];
#pragma unroll
  for (int i = 0; i < 4; ++i)
#pragma unroll
    for (int j = 0; j < 4; ++j) acc[i][j] = (f32x4){0.f, 0.f, 0.f, 0.f};

  // prologue. Queue: A0 A0 A1 A1 B0 B0 B1 B1.
  float4 p0a, p0b, hA, hB;
  loadA(0, p0a, p0b);
  loadA(1, hA, hB);
  stage_B(Bb, lds + B_BASE, 0, wave, lane);
  stage_B(Bb, lds + B_BASE + B_SLOT, 64, wave, lane);
  writeA(0, p0a, p0b);   // compiler inserts vmcnt for A0 only (6 left)
  asm volatile("s_waitcnt vmcnt(2) lgkmcnt(0)" ::: "memory"); // B0+A1 done
  __builtin_amdgcn_s_barrier();

  // K = 512 = 16 ktiles of 32, fully unrolled (static slot indices)
#pragma unroll
  for (int t = 0; t < 16; ++t) {
    if (t > 0) {
      // entry queue (oldest->newest): B(t), A(t+1), B(t+1)
      if (t <= 14) asm volatile("s_waitcnt vmcnt(2) lgkmcnt(0)" ::: "memory");
      else         asm volatile("s_waitcnt vmcnt(0) lgkmcnt(0)" ::: "memory");
      __builtin_amdgcn_s_barrier();
    }

    // A(t+1) fp32 already retired by entry wait: cvt+write with zero stall
    if (t <= 14) writeA(t + 1, hA, hB);

    const int slot = t % 3;
    s16x8 b[4], a[4];
#pragma unroll
    for (int fn = 0; fn < 4; ++fn) b[fn] = rdB(fn, slot);
#pragma unroll
    for (int fm = 0; fm < 4; ++fm) a[fm] = rdA(fm, slot);

    if (t <= 13) {
      loadA(t + 2, hA, hB);   // issue A before B (queue invariant)
      stage_B(Bb, lds + B_BASE + ((t + 2) % 3) * B_SLOT,
              (t + 2) * 64, wave, lane);
    }

    __builtin_amdgcn_s_setprio(1);
#pragma unroll
    for (int fm = 0; fm < 4; ++fm)
#pragma unroll
      for (int fn = 0; fn < 4; ++fn)
        acc[fm][fn] = __builtin_amdgcn_mfma_f32_16x16x32_bf16(
            a[fm], b[fn], acc[fm][fn], 0, 0, 0);
    __builtin_amdgcn_s_setprio(0);
  }

  // epilogue: D lane map (verified): col = lane&15, row = (lane>>4)*4 + reg
  const int mbase = m0 + wm * 64 + ((lane >> 4) << 2);
  const int nbase = n0 + wn * 64 + (lane & 15);
#pragma unroll
  for (int fm = 0; fm < 4; ++fm)
#pragma unroll
    for (int fn = 0; fn < 4; ++fn)
#pragma unroll
      for (int r = 0; r < 4; ++r)
        G[(size_t)(mbase + fm * 16 + r) * 3072 + nbase + fn * 16] =
            __float2bfloat16(acc[fm][fn][r]);
}

// ------------------------------ LN + gates ---------------------------------
__device__ __forceinline__ float4 block_red4(float4 v, float* red, int tid) {
#pragma unroll
  for (int off = 32; off; off >>= 1) {
    v.x += __shfl_down(v.x, off);
    v.y += __shfl_down(v.y, off);
    v.z += __shfl_down(v.z, off);
    v.w += __shfl_down(v.w, off);
  }
  __syncthreads();  // protect `red` against previous use
  if ((tid & 63) == 0) {
    const int w = tid >> 6;
    red[w * 4 + 0] = v.x; red[w * 4 + 1] = v.y;
    red[w * 4 + 2] = v.z; red[w * 4 + 3] = v.w;
  }
  __syncthreads();
  return make_float4(red[0] + red[4] + red[8]  + red[12],
                     red[1] + red[5] + red[9]  + red[13],
                     red[2] + red[6] + red[10] + red[14],
                     red[3] + red[7] + red[11] + red[15]);
}

__global__ __launch_bounds__(256) void ln_gate_kernel(
    const __hip_bfloat16* __restrict__ G, const float* __restrict__ h,
    const float* __restrict__ b0, const float* __restrict__ b1,
    const float* __restrict__ b2, const float* __restrict__ b3,
    float* __restrict__ out)
{
  const int row = blockIdx.x;
  const int t   = threadIdx.x;
  const unsigned short* g = (const unsigned short*)(G + (size_t)row * 3072);

  __shared__ float zr[1024];
  __shared__ float red[16];

  float v0[4], v1[4];
  {
    const ushort4 u = *(const ushort4*)(g + 4 * t);
    const float4 b = *(const float4*)(b0 + 4 * t);
    v0[0] = bfraw2f(u.x) + b.x; v0[1] = bfraw2f(u.y) + b.y;
    v0[2] = bfraw2f(u.z) + b.z; v0[3] = bfraw2f(u.w) + b.w;
  }
  {
    const ushort4 u = *(const ushort4*)(g + 1024 + 4 * t);
    const float4 b = *(const float4*)(b1 + 4 * t);
    v1[0] = bfraw2f(u.x) + b.x; v1[1] = bfraw2f(u.y) + b.y;
    v1[2] = bfraw2f(u.z) + b.z; v1[3] = bfraw2f(u.w) + b.w;
  }
  float4 a;
  a.x = v0[0] + v0[1] + v0[2] + v0[3];
  a.y = v0[0]*v0[0] + v0[1]*v0[1] + v0[2]*v0[2] + v0[3]*v0[3];
  a.z = v1[0] + v1[1] + v1[2] + v1[3];
  a.w = v1[0]*v1[0] + v1[1]*v1[1] + v1[2]*v1[2] + v1[3]*v1[3];
  const float4 r01 = block_red4(a, red, t);
  const float mu0 = r01.x * (1.f / 1024.f);
  const float mu1 = r01.z * (1.f / 1024.f);
  const float rs0 = rsqrtf(r01.y * (1.f / 1024.f) - mu0 * mu0 + 1e-5f);
  const float rs1 = rsqrtf(r01.w * (1.f / 1024.f) - mu1 * mu1 + 1e-5f);

#pragma unroll
  for (int k = 0; k < 4; ++k) {
    const float pre = (v0[k] - mu0) * rs0 + (v1[k] - mu1) * rs1;
    zr[4 * t + k] = 1.f / (1.f + __expf(-pre));
  }

  float v2[2], v3[2];
  {
    const ushort2 u = *(const ushort2*)(g + 2048 + 2 * t);
    const float2 b = *(const float2*)(b2 + 2 * t);
    v2[0] = bfraw2f(u.x) + b.x; v2[1] = bfraw2f(u.y) + b.y;
  }
  {
    const ushort2 u = *(const ushort2*)(g + 2560 + 2 * t);
    const float2 b = *(const float2*)(b3 + 2 * t);
    v3[0] = bfraw2f(u.x) + b.x; v3[1] = bfraw2f(u.y) + b.y;
  }
  a.x = v2[0] + v2[1];
  a.y = v2[0]*v2[0] + v2[1]*v2[1];
  a.z = v3[0] + v3[1];
  a.w = v3[0]*v3[0] + v3[1]*v3[1];
  const float4 r23 = block_red4(a, red, t);  // syncs also publish zr[]
  const float mu2 = r23.x * (1.f / 512.f);
  const float mu3 = r23.z * (1.f / 512.f);
  const float rs2 = rsqrtf(r23.y * (1.f / 512.f) - mu2 * mu2 + 1e-5f);
  const float rs3 = rsqrtf(r23.w * (1.f / 512.f) - mu3 * mu3 + 1e-5f);

  const float2 hv = *(const float2*)(h + (size_t)row * 512 + 2 * t);
  float o[2];
#pragma unroll
  for (int k = 0; k < 2; ++k) {
    const int j = 2 * t + k;
    const float ha = (v2[k] - mu2) * rs2;
    const float hb = (v3[k] - mu3) * rs3;
    const float hhat = tanhf(ha + zr[512 + j] * hb);
    const float z = zr[j];
    const float hvk = (k == 0) ? hv.x : hv.y;
    o[k] = (1.f - z) * hvk + z * hhat;
  }
  *(float2*)(out + (size_t)row * 512 + 2 * t) = make_float2(o[0], o[1]);
}

// ------------------------------- launcher ----------------------------------
extern "C" void kernel_launch(void* const* d_in, const int* in_sizes, int n_in,
                              void* d_out, int out_size, void* d_ws, size_t ws_size,
                              hipStream_t stream) {
  (void)in_sizes; (void)n_in; (void)out_size; (void)ws_size;
  const float* x      = (const float*)d_in[0];
  const float* h      = (const float*)d_in[1];
  const float* W_i2h  = (const float*)d_in[2];
  const float* b_i2h  = (const float*)d_in[3];
  const float* W_h2h  = (const float*)d_in[4];
  const float* b_h2h  = (const float*)d_in[5];
  const float* W_hatW = (const float*)d_in[6];
  const float* b_hatW = (const float*)d_in[7];
  const float* W_hatU = (const float*)d_in[8];
  const float* b_hatU = (const float*)d_in[9];
  float* out = (float*)d_out;
  __hip_bfloat16* ws = (__hip_bfloat16*)d_ws;

  convert_w_kernel<<<1536, 256, 0, stream>>>(W_i2h, W_h2h, W_hatW, W_hatU,
                                             ws + WB_OFF);
  gemm_kernel<<<1536, 512, 0, stream>>>(x, h, ws + WB_OFF, ws + GB_OFF);
  ln_gate_kernel<<<16384, 256, 0, stream>>>(ws + GB_OFF, h, b_i2h, b_h2h,
                                            b_hatW, b_hatU, out);
}